// Round 1
// baseline (181.580 us; speedup 1.0000x reference)
//
#include <hip/hip_runtime.h>

// out[b,h,w,d] = sum_c x[b,h,w,c] * w[c,d]   with C=D=3, fp32.
// Memory-bound: each lane processes 4 pixels = 12 floats = 3x float4
// for both load and store (16B/lane coalesced).

__global__ __launch_bounds__(256) void mct_kernel(
    const float* __restrict__ x,
    const float* __restrict__ w,
    float* __restrict__ out,
    long long n_chunks,      // number of 4-pixel chunks
    long long n_pixels)      // total pixels (for tail)
{
    // 3x3 weight, uniform across lanes (L1-broadcast).
    const float w00 = w[0], w01 = w[1], w02 = w[2];
    const float w10 = w[3], w11 = w[4], w12 = w[5];
    const float w20 = w[6], w21 = w[7], w22 = w[8];

    const long long tid    = (long long)blockIdx.x * blockDim.x + threadIdx.x;
    const long long stride = (long long)gridDim.x * blockDim.x;

    for (long long i = tid; i < n_chunks; i += stride) {
        const float4* src = reinterpret_cast<const float4*>(x) + i * 3;
        float4 a = src[0];
        float4 b = src[1];
        float4 c = src[2];

        float4 oa, ob, oc;
        // pixel 0: (a.x, a.y, a.z)
        oa.x = a.x * w00 + a.y * w10 + a.z * w20;
        oa.y = a.x * w01 + a.y * w11 + a.z * w21;
        oa.z = a.x * w02 + a.y * w12 + a.z * w22;
        // pixel 1: (a.w, b.x, b.y)
        oa.w = a.w * w00 + b.x * w10 + b.y * w20;
        ob.x = a.w * w01 + b.x * w11 + b.y * w21;
        ob.y = a.w * w02 + b.x * w12 + b.y * w22;
        // pixel 2: (b.z, b.w, c.x)
        ob.z = b.z * w00 + b.w * w10 + c.x * w20;
        ob.w = b.z * w01 + b.w * w11 + c.x * w21;
        oc.x = b.z * w02 + b.w * w12 + c.x * w22;
        // pixel 3: (c.y, c.z, c.w)
        oc.y = c.y * w00 + c.z * w10 + c.w * w20;
        oc.z = c.y * w01 + c.z * w11 + c.w * w21;
        oc.w = c.y * w02 + c.z * w12 + c.w * w22;

        float4* dst = reinterpret_cast<float4*>(out) + i * 3;
        dst[0] = oa;
        dst[1] = ob;
        dst[2] = oc;
    }

    // Tail pixels (n_pixels % 4) — empty for the bench shape (8,388,608 % 4 == 0).
    const long long tail_start = n_chunks * 4;
    const long long n_tail     = n_pixels - tail_start;
    if (tid < n_tail) {
        const long long p = tail_start + tid;
        const float x0 = x[p * 3 + 0];
        const float x1 = x[p * 3 + 1];
        const float x2 = x[p * 3 + 2];
        out[p * 3 + 0] = x0 * w00 + x1 * w10 + x2 * w20;
        out[p * 3 + 1] = x0 * w01 + x1 * w11 + x2 * w21;
        out[p * 3 + 2] = x0 * w02 + x1 * w12 + x2 * w22;
    }
}

extern "C" void kernel_launch(void* const* d_in, const int* in_sizes, int n_in,
                              void* d_out, int out_size, void* d_ws, size_t ws_size,
                              hipStream_t stream) {
    const float* x = (const float*)d_in[0];
    const float* w = (const float*)d_in[1];
    float* out = (float*)d_out;

    const long long n_total  = (long long)in_sizes[0];   // 32*512*512*3
    const long long n_pixels = n_total / 3;
    const long long n_chunks = n_pixels / 4;

    const int block = 256;
    long long want = (n_chunks + block - 1) / block;
    int grid = (int)(want < 2048 ? (want > 0 ? want : 1) : 2048);

    mct_kernel<<<grid, block, 0, stream>>>(x, w, out, n_chunks, n_pixels);
}

// Round 3
// 179.327 us; speedup vs baseline: 1.0126x; 1.0126x over previous
//
#include <hip/hip_runtime.h>

// out[b,h,w,d] = sum_c x[b,h,w,c] * w[c,d]   with C=D=3, fp32.
// Memory-bound / latency-bound: one 4-pixel chunk (3x float4 in, 3x float4
// out) per thread, full grid (no grid-stride loop) to maximize TLP.
// R1 lesson: 2048-block grid-stride was latency-bound (Occupancy 47%,
// HBM 30%, dur 63us). Full 8192-block one-chunk-per-thread grid doubles
// resident waves and removes the serial loop.

__global__ __launch_bounds__(256) void mct_kernel(
    const float* __restrict__ x,
    const float* __restrict__ w,
    float* __restrict__ out,
    long long n_chunks,      // number of 4-pixel chunks
    long long n_pixels)      // total pixels (for tail)
{
    const long long i = (long long)blockIdx.x * blockDim.x + threadIdx.x;

    // 3x3 weight, uniform across lanes (scalar loads, L1-broadcast).
    const float w00 = w[0], w01 = w[1], w02 = w[2];
    const float w10 = w[3], w11 = w[4], w12 = w[5];
    const float w20 = w[6], w21 = w[7], w22 = w[8];

    if (i < n_chunks) {
        const float4* src = reinterpret_cast<const float4*>(x) + i * 3;
        float4 a = src[0];
        float4 b = src[1];
        float4 c = src[2];

        float4 oa, ob, oc;
        // pixel 0: (a.x, a.y, a.z)
        oa.x = a.x * w00 + a.y * w10 + a.z * w20;
        oa.y = a.x * w01 + a.y * w11 + a.z * w21;
        oa.z = a.x * w02 + a.y * w12 + a.z * w22;
        // pixel 1: (a.w, b.x, b.y)
        oa.w = a.w * w00 + b.x * w10 + b.y * w20;
        ob.x = a.w * w01 + b.x * w11 + b.y * w21;
        ob.y = a.w * w02 + b.x * w12 + b.y * w22;
        // pixel 2: (b.z, b.w, c.x)
        ob.z = b.z * w00 + b.w * w10 + c.x * w20;
        ob.w = b.z * w01 + b.w * w11 + c.x * w21;
        oc.x = b.z * w02 + b.w * w12 + c.x * w22;
        // pixel 3: (c.y, c.z, c.w)
        oc.y = c.y * w00 + c.z * w10 + c.w * w20;
        oc.z = c.y * w01 + c.z * w11 + c.w * w21;
        oc.w = c.y * w02 + c.z * w12 + c.w * w22;

        float4* dst = reinterpret_cast<float4*>(out) + i * 3;
        dst[0] = oa;
        dst[1] = ob;
        dst[2] = oc;
    }

    // Tail pixels (n_pixels % 4) — empty for the bench shape (8,388,608 % 4 == 0).
    const long long tail_start = n_chunks * 4;
    const long long n_tail     = n_pixels - tail_start;
    if (i < n_tail) {
        const long long p = tail_start + i;
        const float x0 = x[p * 3 + 0];
        const float x1 = x[p * 3 + 1];
        const float x2 = x[p * 3 + 2];
        out[p * 3 + 0] = x0 * w00 + x1 * w10 + x2 * w20;
        out[p * 3 + 1] = x0 * w01 + x1 * w11 + x2 * w21;
        out[p * 3 + 2] = x0 * w02 + x1 * w12 + x2 * w22;
    }
}

extern "C" void kernel_launch(void* const* d_in, const int* in_sizes, int n_in,
                              void* d_out, int out_size, void* d_ws, size_t ws_size,
                              hipStream_t stream) {
    const float* x = (const float*)d_in[0];
    const float* w = (const float*)d_in[1];
    float* out = (float*)d_out;

    const long long n_total  = (long long)in_sizes[0];   // 32*512*512*3
    const long long n_pixels = n_total / 3;
    const long long n_chunks = n_pixels / 4;

    const int block = 256;
    long long grid = (n_chunks + block - 1) / block;     // 8192 for bench shape
    if (grid < 1) grid = 1;

    mct_kernel<<<(int)grid, block, 0, stream>>>(x, w, out, n_chunks, n_pixels);
}

// Round 4
// 177.220 us; speedup vs baseline: 1.0246x; 1.0119x over previous
//
#include <hip/hip_runtime.h>

// out[b,h,w,d] = sum_c x[b,h,w,c] * w[c,d]   with C=D=3, fp32.
//
// R3 lesson: direct strided float4 access (lane stride 48B) capped at
// 2.4 TB/s (30% HBM) regardless of occupancy — per-instruction coalescing
// (48 cache lines/instr vs 16) is the limiter. Fix: stage through LDS so
// every global load/store instruction is stride-1 (lane i <-> float4 i).
//
// Block = 256 threads, chunk = 768 float4 = 1024 pixels = 12 KB LDS.
// Load:   s[tid + k*256] = src[tid + k*256]   (3x, fully coalesced)
// Compute: per-thread in-place (thread t owns s[3t..3t+2]; reads its 12
//          floats to regs, writes 12 results back to the SAME slots — no
//          cross-thread overlap, no extra sync). Lane stride = 12 floats:
//          gcd-free over 32 banks (8 lanes cover all 32) -> conflict-free.
// Store:  dst[tid + k*256] = s[tid + k*256]   (3x, coalesced, nontemporal
//          so output doesn't evict x from L3).

typedef float f4 __attribute__((ext_vector_type(4)));

#define CHUNK_F4 768       // float4s per block
#define CHUNK_PIX 1024     // pixels per block

__global__ __launch_bounds__(256) void mct_kernel(
    const float* __restrict__ x,
    const float* __restrict__ w,
    float* __restrict__ out,
    long long n_full_blocks,
    long long n_pixels)
{
    __shared__ f4 s[CHUNK_F4];
    const int tid = threadIdx.x;
    const long long blk = blockIdx.x;

    // 3x3 weight, uniform (scalar loads, broadcast).
    const float w00 = w[0], w01 = w[1], w02 = w[2];
    const float w10 = w[3], w11 = w[4], w12 = w[5];
    const float w20 = w[6], w21 = w[7], w22 = w[8];

    if (blk < n_full_blocks) {
        const f4* __restrict__ src = reinterpret_cast<const f4*>(x) + blk * CHUNK_F4;
        s[tid      ] = src[tid      ];
        s[tid + 256] = src[tid + 256];
        s[tid + 512] = src[tid + 512];
        __syncthreads();

        f4 a = s[tid * 3 + 0];
        f4 b = s[tid * 3 + 1];
        f4 c = s[tid * 3 + 2];

        f4 oa, ob, oc;
        // pixel 0: (a.x, a.y, a.z)
        oa.x = a.x * w00 + a.y * w10 + a.z * w20;
        oa.y = a.x * w01 + a.y * w11 + a.z * w21;
        oa.z = a.x * w02 + a.y * w12 + a.z * w22;
        // pixel 1: (a.w, b.x, b.y)
        oa.w = a.w * w00 + b.x * w10 + b.y * w20;
        ob.x = a.w * w01 + b.x * w11 + b.y * w21;
        ob.y = a.w * w02 + b.x * w12 + b.y * w22;
        // pixel 2: (b.z, b.w, c.x)
        ob.z = b.z * w00 + b.w * w10 + c.x * w20;
        ob.w = b.z * w01 + b.w * w11 + c.x * w21;
        oc.x = b.z * w02 + b.w * w12 + c.x * w22;
        // pixel 3: (c.y, c.z, c.w)
        oc.y = c.y * w00 + c.z * w10 + c.w * w20;
        oc.z = c.y * w01 + c.z * w11 + c.w * w21;
        oc.w = c.y * w02 + c.z * w12 + c.w * w22;

        // In-place: each thread writes exactly the slots it read.
        s[tid * 3 + 0] = oa;
        s[tid * 3 + 1] = ob;
        s[tid * 3 + 2] = oc;
        __syncthreads();

        f4* dst = reinterpret_cast<f4*>(out) + blk * CHUNK_F4;
        __builtin_nontemporal_store(s[tid      ], dst + tid      );
        __builtin_nontemporal_store(s[tid + 256], dst + tid + 256);
        __builtin_nontemporal_store(s[tid + 512], dst + tid + 512);
    } else {
        // Tail block: scalar per-pixel path (empty for the bench shape).
        long long p = blk * (long long)CHUNK_PIX + tid;
        for (int k = 0; k < 4; ++k, p += 256) {
            if (p < n_pixels) {
                const float x0 = x[p * 3 + 0];
                const float x1 = x[p * 3 + 1];
                const float x2 = x[p * 3 + 2];
                out[p * 3 + 0] = x0 * w00 + x1 * w10 + x2 * w20;
                out[p * 3 + 1] = x0 * w01 + x1 * w11 + x2 * w21;
                out[p * 3 + 2] = x0 * w02 + x1 * w12 + x2 * w22;
            }
        }
    }
}

extern "C" void kernel_launch(void* const* d_in, const int* in_sizes, int n_in,
                              void* d_out, int out_size, void* d_ws, size_t ws_size,
                              hipStream_t stream) {
    const float* x = (const float*)d_in[0];
    const float* w = (const float*)d_in[1];
    float* out = (float*)d_out;

    const long long n_total  = (long long)in_sizes[0];   // 32*512*512*3
    const long long n_pixels = n_total / 3;
    const long long n_full_blocks = n_pixels / CHUNK_PIX;       // 8192 for bench
    const long long tail_pixels   = n_pixels - n_full_blocks * CHUNK_PIX;

    long long grid = n_full_blocks + (tail_pixels > 0 ? 1 : 0);
    if (grid < 1) grid = 1;

    mct_kernel<<<(int)grid, 256, 0, stream>>>(x, w, out, n_full_blocks, n_pixels);
}